// Round 5
// baseline (353.843 us; speedup 1.0000x reference)
//
#include <hip/hip_runtime.h>
#include <math.h>

#define N_PTS 1000000
#define M_COMP 64

typedef float        v2f __attribute__((ext_vector_type(2)));
typedef unsigned int v2u __attribute__((ext_vector_type(2)));

__device__ __forceinline__ float exp2n(float x) { return __builtin_amdgcn_exp2f(x); }
__device__ __forceinline__ float log2n(float x) { return __builtin_amdgcn_logf(x); }

// ---------------------------------------------------------------------------
// Packed exp2: magic-constant range reduction + deg-3 poly + exponent splice.
// All full-rate packed VALU ops — no quarter-rate transcendental stalls.
//   n = round(s) (via y = s + 1.5*2^23, n lives in y's low mantissa bits)
//   f = s - n in [-0.5, 0.5];  2^f ~ deg-3 Horner, rel err < 7e-4
//   result bits = bits(p) + (bits(y) << 23)   [= p * 2^n]
// Clamp at -126 so far components flush to ~1e-38 (harmless, same as fp32
// exp underflow); quadratic form <= 0 so no overflow on the high side.
// ---------------------------------------------------------------------------
__device__ __forceinline__ v2f exp2_pk(v2f s) {
    const float MAGIC = 12582912.0f;  // 1.5 * 2^23
    s = __builtin_elementwise_max(s, (v2f){-126.0f, -126.0f});
    const v2f y = s + (v2f){MAGIC, MAGIC};
    const v2f f = s - (y - (v2f){MAGIC, MAGIC});
    v2f p = __builtin_elementwise_fma(f, (v2f){0.0554906f, 0.0554906f},
                                         (v2f){0.2402265f, 0.2402265f});
    p = __builtin_elementwise_fma(f, p, (v2f){0.6931472f, 0.6931472f});
    p = __builtin_elementwise_fma(f, p, (v2f){1.0f, 1.0f});
    const v2u yb = __builtin_bit_cast(v2u, y);
    const v2u pb = __builtin_bit_cast(v2u, p);
    const v2u rb = pb + (yb << 23);
    return __builtin_bit_cast(v2f, rb);
}

// ---------------------------------------------------------------------------
// Fused kernel. Phase 1 (wave 0): 6 coefficients per component of
//   s_ij = -g00*x0^2 - 2g01*x0*x1 - g11*x1^2 + 2Gmu0*x0 + 2Gmu1*x1
//          + (wlog - mu^T G mu),   all pre-scaled by log2(e)
// into LDS (SoA). Phase 2: 4 points/thread, two packed v2f pipelines,
// components in chunks of 4 via float4 LDS broadcasts, packed software exp2,
// 4 packed accumulators (even/odd comps x 2 pipelines) to shorten add chains.
// Max-free logsumexp (quadratic form <= 0, wlog ~ 0.5).
// ---------------------------------------------------------------------------
__global__ __launch_bounds__(256, 4) void gm_fused(
    const float* __restrict__ sample, // (N,2)
    const float* __restrict__ mu,     // (64,2)
    const float* __restrict__ A,      // (64,2,2)
    const float* __restrict__ w,      // (64,1)
    float* __restrict__ out)          // (N,1)
{
    __shared__ float cf[6 * M_COMP];

    const int tid = threadIdx.x;
    const float L2E = 1.4426950408889634f;
    const float LN2 = 0.6931471805599453f;

    if (tid < 64) {                       // wave 0 exactly
        const int j = tid;
        const float a00 = A[j*4+0], a01 = A[j*4+1], a10 = A[j*4+2], a11 = A[j*4+3];
        const float g00 = 0.5f*(a00*a00 + a01*a01);
        const float g01 = 0.5f*(a00*a10 + a01*a11);
        const float g11 = 0.5f*(a10*a10 + a11*a11);
        const float det = g00*g11 - g01*g01;

        const float m0 = mu[j*2+0], m1 = mu[j*2+1];
        const float Gmu0 = g00*m0 + g01*m1;
        const float Gmu1 = g01*m0 + g11*m1;
        const float cst  = m0*Gmu0 + m1*Gmu1;

        const float wj = w[j];
        float mx = wj;
        #pragma unroll
        for (int m = 1; m < 64; m <<= 1)
            mx = fmaxf(mx, __shfl_xor(mx, m, 64));
        float se = exp2n((wj - mx) * L2E);
        #pragma unroll
        for (int m = 1; m < 64; m <<= 1)
            se += __shfl_xor(se, m, 64);
        const float lse  = mx + log2n(se) * LN2;
        const float wlog = wj - lse + 0.5f * log2n(det) * LN2;

        cf[0*M_COMP+j] = -g00 * L2E;
        cf[1*M_COMP+j] = -(g01+g01) * L2E;
        cf[2*M_COMP+j] = -g11 * L2E;
        cf[3*M_COMP+j] = (Gmu0+Gmu0) * L2E;
        cf[4*M_COMP+j] = (Gmu1+Gmu1) * L2E;
        cf[5*M_COMP+j] = (wlog - cst) * L2E;
    }
    __syncthreads();

    const int t  = blockIdx.x * 256 + tid;   // 4 points per thread
    const int p0 = t * 4;
    const bool ok = p0 < N_PTS;
    const int  pl = ok ? p0 : 0;             // clamp OOB, keep wave intact

    const float4* s4 = (const float4*)sample;
    const float4 qa = s4[(pl >> 1) + 0];     // points p0, p0+1
    const float4 qb = s4[(pl >> 1) + 1];     // points p0+2, p0+3

    const v2f ax0 = {qa.x, qa.z}, ax1 = {qa.y, qa.w};
    const v2f bx0 = {qb.x, qb.z}, bx1 = {qb.y, qb.w};
    const v2f axx0 = ax0*ax0, ax01 = ax0*ax1, axx1 = ax1*ax1;
    const v2f bxx0 = bx0*bx0, bx01 = bx0*bx1, bxx1 = bx1*bx1;

    v2f accA0 = {0.f, 0.f}, accA1 = {0.f, 0.f};   // pipeline A, even/odd comps
    v2f accB0 = {0.f, 0.f}, accB1 = {0.f, 0.f};   // pipeline B, even/odd comps

    #pragma unroll
    for (int jc = 0; jc < M_COMP; jc += 4) {
        const float4 c0 = *(const float4*)&cf[0*M_COMP+jc];
        const float4 c1 = *(const float4*)&cf[1*M_COMP+jc];
        const float4 c2 = *(const float4*)&cf[2*M_COMP+jc];
        const float4 c3 = *(const float4*)&cf[3*M_COMP+jc];
        const float4 c4 = *(const float4*)&cf[4*M_COMP+jc];
        const float4 c5 = *(const float4*)&cf[5*M_COMP+jc];

#define GM_COMP(F, ACCA, ACCB)                                          \
        {                                                               \
            v2f s = {c5.F, c5.F};                                       \
            s = __builtin_elementwise_fma(ax1,  (v2f){c4.F, c4.F}, s);  \
            s = __builtin_elementwise_fma(ax0,  (v2f){c3.F, c3.F}, s);  \
            s = __builtin_elementwise_fma(axx1, (v2f){c2.F, c2.F}, s);  \
            s = __builtin_elementwise_fma(ax01, (v2f){c1.F, c1.F}, s);  \
            s = __builtin_elementwise_fma(axx0, (v2f){c0.F, c0.F}, s);  \
            ACCA += exp2_pk(s);                                         \
            v2f r = {c5.F, c5.F};                                       \
            r = __builtin_elementwise_fma(bx1,  (v2f){c4.F, c4.F}, r);  \
            r = __builtin_elementwise_fma(bx0,  (v2f){c3.F, c3.F}, r);  \
            r = __builtin_elementwise_fma(bxx1, (v2f){c2.F, c2.F}, r);  \
            r = __builtin_elementwise_fma(bx01, (v2f){c1.F, c1.F}, r);  \
            r = __builtin_elementwise_fma(bxx0, (v2f){c0.F, c0.F}, r);  \
            ACCB += exp2_pk(r);                                         \
        }
        GM_COMP(x, accA0, accB0)
        GM_COMP(y, accA1, accB1)
        GM_COMP(z, accA0, accB0)
        GM_COMP(w, accA1, accB1)
#undef GM_COMP
    }

    if (ok) {
        const v2f accA = accA0 + accA1;
        const v2f accB = accB0 + accB1;
        float4 o;
        o.x = log2n(accA[0]) * LN2;
        o.y = log2n(accA[1]) * LN2;
        o.z = log2n(accB[0]) * LN2;
        o.w = log2n(accB[1]) * LN2;
        *(float4*)&out[p0] = o;
    }
}

extern "C" void kernel_launch(void* const* d_in, const int* in_sizes, int n_in,
                              void* d_out, int out_size, void* d_ws, size_t ws_size,
                              hipStream_t stream)
{
    const float* sample = (const float*)d_in[0];  // (1e6, 2) f32
    const float* mu     = (const float*)d_in[1];  // (64, 2)  f32
    const float* A      = (const float*)d_in[2];  // (64,2,2) f32
    const float* w      = (const float*)d_in[3];  // (64, 1)  f32
    float* out = (float*)d_out;                   // (1e6, 1) f32

    const int threads = N_PTS / 4;                // 4 points per thread
    const int blocks  = (threads + 255) / 256;    // 977
    gm_fused<<<blocks, 256, 0, stream>>>(sample, mu, A, w, out);
}

// Round 6
// 23.839 us; speedup vs baseline: 14.8429x; 14.8429x over previous
//
#include <hip/hip_runtime.h>
#include <math.h>

#define N_PTS 1000000
#define M_COMP 64

typedef float        v2f __attribute__((ext_vector_type(2)));
typedef unsigned int v2u __attribute__((ext_vector_type(2)));

__device__ __forceinline__ float exp2n(float x) { return __builtin_amdgcn_exp2f(x); }
__device__ __forceinline__ float log2n(float x) { return __builtin_amdgcn_logf(x); }

// ---------------------------------------------------------------------------
// Packed exp2: magic-constant range reduction + deg-3 poly + exponent splice.
// All full-rate packed VALU ops — no quarter-rate transcendental stalls.
//   n = round(s) (via y = s + 1.5*2^23, n in y's low mantissa bits)
//   f = s - n in [-0.5, 0.5];  2^f ~ deg-3 Horner, rel err < 7e-4
//   result bits = bits(p) + (bits(y) << 23)   [= p * 2^n]
// Clamp at -126: far components flush to ~1e-38 (harmless; same as fp32 exp
// underflow). Quadratic form <= 0, so no overflow on the high side.
// ---------------------------------------------------------------------------
__device__ __forceinline__ v2f exp2_pk(v2f s) {
    const float MAGIC = 12582912.0f;  // 1.5 * 2^23
    s = __builtin_elementwise_max(s, (v2f){-126.0f, -126.0f});
    const v2f y = s + (v2f){MAGIC, MAGIC};
    const v2f f = s - (y - (v2f){MAGIC, MAGIC});
    v2f p = __builtin_elementwise_fma(f, (v2f){0.0554906f, 0.0554906f},
                                         (v2f){0.2402265f, 0.2402265f});
    p = __builtin_elementwise_fma(f, p, (v2f){0.6931472f, 0.6931472f});
    p = __builtin_elementwise_fma(f, p, (v2f){1.0f, 1.0f});
    const v2u yb = __builtin_bit_cast(v2u, y);
    const v2u pb = __builtin_bit_cast(v2u, p);
    const v2u rb = pb + (yb << 23);
    return __builtin_bit_cast(v2f, rb);
}

// ---------------------------------------------------------------------------
// Fused kernel. Phase 1 (wave 0): 6 coefficients per component of
//   s_ij = -g00*x0^2 - 2g01*x0*x1 - g11*x1^2 + 2Gmu0*x0 + 2Gmu1*x1
//          + (wlog - mu^T G mu),   all pre-scaled by log2(e)
// into LDS (SoA). Phase 2: 4 points/thread, two packed v2f pipelines,
// components in chunks of 4 via float4 LDS broadcasts, packed software exp2,
// 4 packed accumulators (even/odd comps x 2 pipelines).
// Max-free logsumexp (quadratic form <= 0, wlog ~ 0.5).
//
// NOTE: bounded unroll (4) and NO min-occupancy launch_bounds clause — the
// full-unroll + VGPR-cap combo in the previous round made the allocator
// spill ~2 KB/thread to scratch (500 MB of HBM spill traffic, 20x slowdown).
// ---------------------------------------------------------------------------
__global__ __launch_bounds__(256) void gm_fused(
    const float* __restrict__ sample, // (N,2)
    const float* __restrict__ mu,     // (64,2)
    const float* __restrict__ A,      // (64,2,2)
    const float* __restrict__ w,      // (64,1)
    float* __restrict__ out)          // (N,1)
{
    __shared__ float cf[6 * M_COMP];

    const int tid = threadIdx.x;
    const float L2E = 1.4426950408889634f;
    const float LN2 = 0.6931471805599453f;

    if (tid < 64) {                       // wave 0 exactly
        const int j = tid;
        const float a00 = A[j*4+0], a01 = A[j*4+1], a10 = A[j*4+2], a11 = A[j*4+3];
        const float g00 = 0.5f*(a00*a00 + a01*a01);
        const float g01 = 0.5f*(a00*a10 + a01*a11);
        const float g11 = 0.5f*(a10*a10 + a11*a11);
        const float det = g00*g11 - g01*g01;

        const float m0 = mu[j*2+0], m1 = mu[j*2+1];
        const float Gmu0 = g00*m0 + g01*m1;
        const float Gmu1 = g01*m0 + g11*m1;
        const float cst  = m0*Gmu0 + m1*Gmu1;

        const float wj = w[j];
        float mx = wj;
        #pragma unroll
        for (int m = 1; m < 64; m <<= 1)
            mx = fmaxf(mx, __shfl_xor(mx, m, 64));
        float se = exp2n((wj - mx) * L2E);
        #pragma unroll
        for (int m = 1; m < 64; m <<= 1)
            se += __shfl_xor(se, m, 64);
        const float lse  = mx + log2n(se) * LN2;
        const float wlog = wj - lse + 0.5f * log2n(det) * LN2;

        cf[0*M_COMP+j] = -g00 * L2E;
        cf[1*M_COMP+j] = -(g01+g01) * L2E;
        cf[2*M_COMP+j] = -g11 * L2E;
        cf[3*M_COMP+j] = (Gmu0+Gmu0) * L2E;
        cf[4*M_COMP+j] = (Gmu1+Gmu1) * L2E;
        cf[5*M_COMP+j] = (wlog - cst) * L2E;
    }
    __syncthreads();

    const int t  = blockIdx.x * 256 + tid;   // 4 points per thread
    const int p0 = t * 4;
    const bool ok = p0 < N_PTS;
    const int  pl = ok ? p0 : 0;             // clamp OOB, keep wave intact

    const float4* s4 = (const float4*)sample;
    const float4 qa = s4[(pl >> 1) + 0];     // points p0, p0+1
    const float4 qb = s4[(pl >> 1) + 1];     // points p0+2, p0+3

    const v2f ax0 = {qa.x, qa.z}, ax1 = {qa.y, qa.w};
    const v2f bx0 = {qb.x, qb.z}, bx1 = {qb.y, qb.w};
    const v2f axx0 = ax0*ax0, ax01 = ax0*ax1, axx1 = ax1*ax1;
    const v2f bxx0 = bx0*bx0, bx01 = bx0*bx1, bxx1 = bx1*bx1;

    v2f accA0 = {0.f, 0.f}, accA1 = {0.f, 0.f};   // pipeline A, even/odd comps
    v2f accB0 = {0.f, 0.f}, accB1 = {0.f, 0.f};   // pipeline B, even/odd comps

    #pragma unroll 4
    for (int jc = 0; jc < M_COMP; jc += 4) {
        const float4 c0 = *(const float4*)&cf[0*M_COMP+jc];
        const float4 c1 = *(const float4*)&cf[1*M_COMP+jc];
        const float4 c2 = *(const float4*)&cf[2*M_COMP+jc];
        const float4 c3 = *(const float4*)&cf[3*M_COMP+jc];
        const float4 c4 = *(const float4*)&cf[4*M_COMP+jc];
        const float4 c5 = *(const float4*)&cf[5*M_COMP+jc];

#define GM_COMP(F, ACCA, ACCB)                                          \
        {                                                               \
            v2f s = {c5.F, c5.F};                                       \
            s = __builtin_elementwise_fma(ax1,  (v2f){c4.F, c4.F}, s);  \
            s = __builtin_elementwise_fma(ax0,  (v2f){c3.F, c3.F}, s);  \
            s = __builtin_elementwise_fma(axx1, (v2f){c2.F, c2.F}, s);  \
            s = __builtin_elementwise_fma(ax01, (v2f){c1.F, c1.F}, s);  \
            s = __builtin_elementwise_fma(axx0, (v2f){c0.F, c0.F}, s);  \
            ACCA += exp2_pk(s);                                         \
            v2f r = {c5.F, c5.F};                                       \
            r = __builtin_elementwise_fma(bx1,  (v2f){c4.F, c4.F}, r);  \
            r = __builtin_elementwise_fma(bx0,  (v2f){c3.F, c3.F}, r);  \
            r = __builtin_elementwise_fma(bxx1, (v2f){c2.F, c2.F}, r);  \
            r = __builtin_elementwise_fma(bx01, (v2f){c1.F, c1.F}, r);  \
            r = __builtin_elementwise_fma(bxx0, (v2f){c0.F, c0.F}, r);  \
            ACCB += exp2_pk(r);                                         \
        }
        GM_COMP(x, accA0, accB0)
        GM_COMP(y, accA1, accB1)
        GM_COMP(z, accA0, accB0)
        GM_COMP(w, accA1, accB1)
#undef GM_COMP
    }

    if (ok) {
        const v2f accA = accA0 + accA1;
        const v2f accB = accB0 + accB1;
        float4 o;
        o.x = log2n(accA[0]) * LN2;
        o.y = log2n(accA[1]) * LN2;
        o.z = log2n(accB[0]) * LN2;
        o.w = log2n(accB[1]) * LN2;
        *(float4*)&out[p0] = o;
    }
}

extern "C" void kernel_launch(void* const* d_in, const int* in_sizes, int n_in,
                              void* d_out, int out_size, void* d_ws, size_t ws_size,
                              hipStream_t stream)
{
    const float* sample = (const float*)d_in[0];  // (1e6, 2) f32
    const float* mu     = (const float*)d_in[1];  // (64, 2)  f32
    const float* A      = (const float*)d_in[2];  // (64,2,2) f32
    const float* w      = (const float*)d_in[3];  // (64, 1)  f32
    float* out = (float*)d_out;                   // (1e6, 1) f32

    const int threads = N_PTS / 4;                // 4 points per thread
    const int blocks  = (threads + 255) / 256;    // 977
    gm_fused<<<blocks, 256, 0, stream>>>(sample, mu, A, w, out);
}

// Round 7
// 22.043 us; speedup vs baseline: 16.0526x; 1.0815x over previous
//
#include <hip/hip_runtime.h>
#include <math.h>

#define N_PTS 1000000
#define M_COMP 64

typedef float v2f __attribute__((ext_vector_type(2)));

__device__ __forceinline__ float exp2n(float x) { return __builtin_amdgcn_exp2f(x); }
__device__ __forceinline__ float log2n(float x) { return __builtin_amdgcn_logf(x); }

// ---------------------------------------------------------------------------
// Kernel 1 (1 block, 64 threads): per-component coefficients of
//   s_ij = -g00*x0^2 - 2g01*x0*x1 - g11*x1^2 + 2Gmu0*x0 + 2Gmu1*x1
//          + (wlog - mu^T G mu),   all pre-scaled by log2(e),
// written SoA cf[k][64] to GLOBAL d_ws. Global (not LDS) so the main kernel
// can read them with wave-uniform addresses -> s_load into SGPRs: zero VALU
// issue cost, no splat v_movs (v_pk_fma takes one SGPR broadcast operand),
// no ds_read/lgkmcnt stalls on the vector critical path.
// ---------------------------------------------------------------------------
__global__ __launch_bounds__(64) void gm_coef(
    const float* __restrict__ mu,   // (64,2)
    const float* __restrict__ A,    // (64,2,2)
    const float* __restrict__ w,    // (64,1)
    float* __restrict__ cf)         // (6,64) in d_ws
{
    const int j = threadIdx.x;
    const float L2E = 1.4426950408889634f;
    const float LN2 = 0.6931471805599453f;

    const float a00 = A[j*4+0], a01 = A[j*4+1], a10 = A[j*4+2], a11 = A[j*4+3];
    const float g00 = 0.5f*(a00*a00 + a01*a01);
    const float g01 = 0.5f*(a00*a10 + a01*a11);
    const float g11 = 0.5f*(a10*a10 + a11*a11);
    const float det = g00*g11 - g01*g01;

    const float m0 = mu[j*2+0], m1 = mu[j*2+1];
    const float Gmu0 = g00*m0 + g01*m1;
    const float Gmu1 = g01*m0 + g11*m1;
    const float cst  = m0*Gmu0 + m1*Gmu1;

    const float wj = w[j];
    float mx = wj;
    #pragma unroll
    for (int m = 1; m < 64; m <<= 1)
        mx = fmaxf(mx, __shfl_xor(mx, m, 64));
    float se = exp2n((wj - mx) * L2E);
    #pragma unroll
    for (int m = 1; m < 64; m <<= 1)
        se += __shfl_xor(se, m, 64);
    const float lse  = mx + log2n(se) * LN2;
    const float wlog = wj - lse + 0.5f * log2n(det) * LN2;

    cf[0*M_COMP+j] = -g00 * L2E;
    cf[1*M_COMP+j] = -(g01+g01) * L2E;
    cf[2*M_COMP+j] = -g11 * L2E;
    cf[3*M_COMP+j] = (Gmu0+Gmu0) * L2E;
    cf[4*M_COMP+j] = (Gmu1+Gmu1) * L2E;
    cf[5*M_COMP+j] = (wlog - cst) * L2E;
}

// ---------------------------------------------------------------------------
// Kernel 2: 4 points per thread, two packed v2f pipelines. Coefficients come
// from global memory with wave-uniform indices (SGPRs). Native v_exp_f32.
// Max-free logsumexp: quadratic form <= 0, wlog ~ 0.5 => exp2 args bounded
// above by ~1.5; far components flush to 0 harmlessly in fp32.
// unroll 2: 2 chunks x 24 coef floats = <=48 live coef SGPRs, no pressure
// blow-up (R5 lesson: aggressive unroll + pressure cap => 2 KB/thread spill).
// ---------------------------------------------------------------------------
__global__ __launch_bounds__(256) void gm_ll(
    const float* __restrict__ sample, // (N,2)
    const float* __restrict__ cf,     // (6,64) in d_ws
    float* __restrict__ out)          // (N,1)
{
    const float LN2 = 0.6931471805599453f;

    const int t  = blockIdx.x * 256 + threadIdx.x;   // 4 points per thread
    const int p0 = t * 4;
    const bool ok = p0 < N_PTS;
    const int  pl = ok ? p0 : 0;             // clamp OOB, keep wave intact

    const float4* s4 = (const float4*)sample;
    const float4 qa = s4[(pl >> 1) + 0];     // points p0, p0+1
    const float4 qb = s4[(pl >> 1) + 1];     // points p0+2, p0+3

    const v2f ax0 = {qa.x, qa.z}, ax1 = {qa.y, qa.w};
    const v2f bx0 = {qb.x, qb.z}, bx1 = {qb.y, qb.w};
    const v2f axx0 = ax0*ax0, ax01 = ax0*ax1, axx1 = ax1*ax1;
    const v2f bxx0 = bx0*bx0, bx01 = bx0*bx1, bxx1 = bx1*bx1;

    v2f accA = {0.f, 0.f};
    v2f accB = {0.f, 0.f};

    #pragma unroll 2
    for (int jc = 0; jc < M_COMP; jc += 4) {
        #pragma unroll
        for (int u = 0; u < 4; ++u) {
            // Wave-uniform scalar loads -> SGPRs (s_load_dwordx4 batches).
            const float c0 = cf[0*M_COMP + jc + u];
            const float c1 = cf[1*M_COMP + jc + u];
            const float c2 = cf[2*M_COMP + jc + u];
            const float c3 = cf[3*M_COMP + jc + u];
            const float c4 = cf[4*M_COMP + jc + u];
            const float c5 = cf[5*M_COMP + jc + u];

            v2f s = {c5, c5};
            s = __builtin_elementwise_fma(ax1,  (v2f){c4, c4}, s);
            s = __builtin_elementwise_fma(ax0,  (v2f){c3, c3}, s);
            s = __builtin_elementwise_fma(axx1, (v2f){c2, c2}, s);
            s = __builtin_elementwise_fma(ax01, (v2f){c1, c1}, s);
            s = __builtin_elementwise_fma(axx0, (v2f){c0, c0}, s);
            accA[0] += exp2n(s[0]);
            accA[1] += exp2n(s[1]);

            v2f r = {c5, c5};
            r = __builtin_elementwise_fma(bx1,  (v2f){c4, c4}, r);
            r = __builtin_elementwise_fma(bx0,  (v2f){c3, c3}, r);
            r = __builtin_elementwise_fma(bxx1, (v2f){c2, c2}, r);
            r = __builtin_elementwise_fma(bx01, (v2f){c1, c1}, r);
            r = __builtin_elementwise_fma(bxx0, (v2f){c0, c0}, r);
            accB[0] += exp2n(r[0]);
            accB[1] += exp2n(r[1]);
        }
    }

    if (ok) {
        float4 o;
        o.x = log2n(accA[0]) * LN2;
        o.y = log2n(accA[1]) * LN2;
        o.z = log2n(accB[0]) * LN2;
        o.w = log2n(accB[1]) * LN2;
        *(float4*)&out[p0] = o;
    }
}

extern "C" void kernel_launch(void* const* d_in, const int* in_sizes, int n_in,
                              void* d_out, int out_size, void* d_ws, size_t ws_size,
                              hipStream_t stream)
{
    const float* sample = (const float*)d_in[0];  // (1e6, 2) f32
    const float* mu     = (const float*)d_in[1];  // (64, 2)  f32
    const float* A      = (const float*)d_in[2];  // (64,2,2) f32
    const float* w      = (const float*)d_in[3];  // (64, 1)  f32
    float* out = (float*)d_out;                   // (1e6, 1) f32
    float* cf  = (float*)d_ws;                    // 6*64 floats = 1.5 KB

    gm_coef<<<1, 64, 0, stream>>>(mu, A, w, cf);

    const int threads = N_PTS / 4;                // 4 points per thread
    const int blocks  = (threads + 255) / 256;    // 977
    gm_ll<<<blocks, 256, 0, stream>>>(sample, cf, out);
}